// Round 9
// baseline (563.004 us; speedup 1.0000x reference)
//
#include <hip/hip_runtime.h>

typedef unsigned short u16;
typedef unsigned int   u32;
typedef __attribute__((ext_vector_type(8))) short short8;
typedef __attribute__((ext_vector_type(4))) float float4v;
typedef __attribute__((ext_vector_type(2))) float float2v;
typedef __attribute__((ext_vector_type(4), aligned(4))) float float4u;   // dword-aligned vec load

#define NODE_D   38
#define EDGE_D   13
#define D_OUT    128
#define NEG_SLOPE 0.2f
#define LN_EPS   1e-5f
#define SPW      4       // slots per wave in k_logit

__device__ __forceinline__ float bf2f(u16 v) { return __uint_as_float(((u32)v) << 16); }
__device__ __forceinline__ u16 f2bf(float f) {
    u32 u = __float_as_uint(f);
    u += 0x7fffu + ((u >> 16) & 1u);   // round-to-nearest-even
    return (u16)(u >> 16);
}

// ---- DPP 16-lane all-reduce: 4 VALU adds, no LDS pipe, no lgkm waits ----
template <int CTRL>
__device__ __forceinline__ float dpp_radd(float x) {
    int t = __builtin_amdgcn_update_dpp(0, __float_as_int(x), CTRL, 0xf, 0xf, true);
    return x + __int_as_float(t);
}
__device__ __forceinline__ float reduce16(float p) {
    p = dpp_radd<0xB1>(p);    // quad_perm [1,0,3,2]  : xor 1
    p = dpp_radd<0x4E>(p);    // quad_perm [2,3,0,1]  : xor 2
    p = dpp_radd<0x124>(p);   // row_ror:4
    p = dpp_radd<0x128>(p);   // row_ror:8 -> all 16 lanes hold group sum
    return p;
}
__device__ __forceinline__ float reduce64(float v) {
    v = reduce16(v);
    v += __shfl_xor(v, 16, 64);
    v += __shfl_xor(v, 32, 64);
    return v;
}

// ---------------- fused: degree count + graph offsets + x->bf16 cast ----------------
__global__ void k_pre(const int* __restrict__ dst, int E, int* __restrict__ deg,
                      const int* __restrict__ batch, int N, int G, int* __restrict__ goff,
                      const float* __restrict__ x, u16* __restrict__ xb) {
    int i = blockIdx.x * blockDim.x + threadIdx.x;
    if (i < E) atomicAdd(deg + dst[i], 1);
    if (i < N) {
        int b = batch[i];
        int prev = (i == 0) ? -1 : batch[i - 1];
        for (int g = prev + 1; g <= b; g++) goff[g] = i;
        if (i == N - 1)
            for (int g = b + 1; g <= G; g++) goff[g] = N;
    }
    if (i < N * 32) {   // x (f32, 38 wide) -> bf16 rows padded to 64
        int n = i >> 5, kk = (i & 31) * 2;
        float f0 = 0.f, f1 = 0.f;
        if (kk < NODE_D) {   // NODE_D even -> pair never straddles row end; 8B-aligned
            float2v v = *(const float2v*)(x + (size_t)n * NODE_D + kk);
            f0 = v[0]; f1 = v[1];
        }
        ((u32*)xb)[(size_t)n * 32 + (i & 31)] = (u32)f2bf(f0) | ((u32)f2bf(f1) << 16);
    }
}

// ---------------- multi-block exclusive scan (chunk = 1024), adds `addone` per elem ----------------
#define SCAN_CHUNK 1024
__global__ void k_scan1(const int* __restrict__ cnt, int N, int addone, int* __restrict__ bsum) {
    __shared__ int sh[256];
    int base = blockIdx.x * SCAN_CHUNK;
    int t = threadIdx.x;
    int s = 0;
#pragma unroll
    for (int i = 0; i < 4; i++) { int idx = base + t * 4 + i; if (idx < N) s += cnt[idx] + addone; }
    sh[t] = s; __syncthreads();
    for (int ofs = 128; ofs > 0; ofs >>= 1) {
        if (t < ofs) sh[t] += sh[t + ofs];
        __syncthreads();
    }
    if (t == 0) bsum[blockIdx.x] = sh[0];
}
__global__ void k_scan2(const int* __restrict__ bsum, int nb, int* __restrict__ boff) {
    __shared__ int sh[256];
    int t = threadIdx.x;
    if (nb <= 256) {
        int v = (t < nb) ? bsum[t] : 0;
        sh[t] = v; __syncthreads();
        for (int ofs = 1; ofs < 256; ofs <<= 1) {
            int x = (t >= ofs) ? sh[t - ofs] : 0;
            __syncthreads();
            sh[t] += x;
            __syncthreads();
        }
        if (t < nb) boff[t] = sh[t] - v;       // exclusive
        if (t == nb - 1) boff[nb] = sh[t];     // total
    } else if (t == 0) {
        int run = 0;
        for (int i = 0; i < nb; i++) { boff[i] = run; run += bsum[i]; }
        boff[nb] = run;
    }
}
__global__ void k_scan3(const int* __restrict__ cnt, int N, int addone,
                        const int* __restrict__ boff, int nb, int* __restrict__ off) {
    __shared__ int wtot[4];
    int base = blockIdx.x * SCAN_CHUNK;
    int t = threadIdx.x;
    int lane = t & 63, w = t >> 6;
    int v[4]; int s = 0;
#pragma unroll
    for (int i = 0; i < 4; i++) { int idx = base + t * 4 + i; v[i] = (idx < N) ? cnt[idx] + addone : 0; s += v[i]; }
    int inc = s;
#pragma unroll
    for (int ofs = 1; ofs < 64; ofs <<= 1) {
        int x = __shfl_up(inc, ofs, 64);
        if (lane >= ofs) inc += x;
    }
    if (lane == 63) wtot[w] = inc;
    __syncthreads();
    int wofs = 0;
    for (int i = 0; i < w; i++) wofs += wtot[i];
    int run = boff[blockIdx.x] + wofs + (inc - s);
#pragma unroll
    for (int i = 0; i < 4; i++) {
        int idx = base + t * 4 + i;
        if (idx < N) off[idx] = run;
        run += v[i];
    }
    if (blockIdx.x == 0 && t == 0) off[N] = boff[nb];
}

// ---------------- CSR fill: scatter src, dst AND the bf16 A-row (16-wide, padded) ----------
__global__ void k_fill(const int* __restrict__ src, const int* __restrict__ dst,
                       const float* __restrict__ eattr, int E,
                       const int* __restrict__ csr_off, int* __restrict__ fill,
                       int* __restrict__ csr_src, int* __restrict__ dst_csr,
                       u16* __restrict__ A) {
    int e = blockIdx.x * blockDim.x + threadIdx.x;
    if (e >= E) return;
    int d = dst[e];
    int pos = csr_off[d] + atomicAdd(fill + d, 1);
    csr_src[pos] = src[e];
    dst_csr[pos] = d;
    const float* ep = eattr + (size_t)e * EDGE_D;
    float4u v0 = *(const float4u*)(ep);          // dwordx4, dword-aligned
    float4u v1 = *(const float4u*)(ep + 4);
    float4u v2 = *(const float4u*)(ep + 8);
    float   v3 = ep[12];
    u16 row[16];
#pragma unroll
    for (int k = 0; k < 4; k++) { row[k] = f2bf(v0[k]); row[4 + k] = f2bf(v1[k]); row[8 + k] = f2bf(v2[k]); }
    row[12] = f2bf(v3);
#pragma unroll
    for (int k = EDGE_D; k < 16; k++) row[k] = 0;
    uint4* rp = (uint4*)(A + (size_t)pos * 16);
    rp[0] = (uint4){(u32)row[0] | ((u32)row[1] << 16), (u32)row[2] | ((u32)row[3] << 16),
                    (u32)row[4] | ((u32)row[5] << 16), (u32)row[6] | ((u32)row[7] << 16)};
    rp[1] = (uint4){(u32)row[8] | ((u32)row[9] << 16), (u32)row[10] | ((u32)row[11] << 16),
                    (u32)row[12] | ((u32)row[13] << 16), (u32)row[14] | ((u32)row[15] << 16)};
}

// ---------------- self rows: one WAVE per node, coalesced 4-row x 16-ch lanes ----------------
__global__ __launch_bounds__(256) void k_self(const int* __restrict__ csr_off, int N,
                                              int* __restrict__ csr_src, int* __restrict__ dst_csr,
                                              u16* __restrict__ A) {
    int wave = blockIdx.x * 4 + (threadIdx.x >> 6);
    if (wave >= N) return;
    int lane = threadIdx.x & 63;
    int r = lane >> 4, k = lane & 15;
    int b = csr_off[wave], e2 = csr_off[wave + 1] - 1;   // e2 = self slot
    float s = 0.f;
    for (int j = b + r; j < e2; j += 4)                  // lanes cover 4 rows x 16 ch: 128B/iter
        s += bf2f(A[(size_t)j * 16 + k]);
    s += __shfl_xor(s, 16, 64);
    s += __shfl_xor(s, 32, 64);
    if (lane < 16) {
        u16 v = (k < EDGE_D) ? f2bf(s / fmaxf((float)(e2 - b), 1.f)) : (u16)0;
        A[(size_t)e2 * 16 + k] = v;
        if (k == 0) { csr_src[e2] = wave; dst_csr[e2] = wave; }
    }
}

// ---------------- MFMA multi-output transform (transposed store: 8B ushort4 per lane) ------
template <int KPAD, int CT, int KREAL, bool IN_BF16>
__global__ __launch_bounds__(256) void k_tf_mfma(
    const void* __restrict__ in_v,
    const float* __restrict__ W0, const float* __restrict__ b0,
    const float* __restrict__ W1, const float* __restrict__ b1,
    const float* __restrict__ W2, const float* __restrict__ b2,
    u16* __restrict__ o0, u16* __restrict__ o1, u16* __restrict__ o2,
    int N) {
    constexpr int RS = KPAD + 8;
    __shared__ u16 Bsw[CT * 16 * RS];
    __shared__ float bsh[CT * 16];
    const float* Ws[3] = {W0, W1, W2};
    const float* bs[3] = {b0, b1, b2};
    u16* outs[3] = {o0, o1, o2};
    int t = threadIdx.x;
    for (int i = t; i < CT * 16 * KPAD; i += 256) {
        int c = i / KPAD, k = i - c * KPAD;
        float v = (k < KREAL) ? Ws[c >> 7][(size_t)k * 128 + (c & 127)] : 0.f;
        Bsw[c * RS + k] = f2bf(v);
    }
    for (int i = t; i < CT * 16; i += 256) bsh[i] = bs[i >> 7][i & 127];
    __syncthreads();

    int wid = t >> 6, lane = t & 63;
    int quad = lane >> 4, m = lane & 15;

    for (int g0 = blockIdx.x * 64; g0 < N; g0 += gridDim.x * 64) {
        int na = g0 + wid * 16 + m;
        if (na > N - 1) na = N - 1;
        short8 a[KPAD / 32];
        if (IN_BF16) {
            const u16* in = (const u16*)in_v;
#pragma unroll
            for (int kc = 0; kc < KPAD / 32; kc++)
                a[kc] = *(const short8*)(in + (size_t)na * KPAD + kc * 32 + quad * 8);
        } else {
            const float* in = (const float*)in_v;
#pragma unroll
            for (int kc = 0; kc < KPAD / 32; kc++)
#pragma unroll
                for (int j = 0; j < 8; j++) {
                    int k = kc * 32 + quad * 8 + j;
                    float v = (k < KREAL) ? in[(size_t)na * KREAL + k] : 0.f;
                    a[kc][j] = (short)f2bf(v);
                }
        }
        float4v acc[CT];
#pragma unroll
        for (int ct = 0; ct < CT; ct++) acc[ct] = (float4v){0.f, 0.f, 0.f, 0.f};
#pragma unroll
        for (int ct = 0; ct < CT; ct++) {
#pragma unroll
            for (int kc = 0; kc < KPAD / 32; kc++) {
                short8 b = *(const short8*)(&Bsw[(ct * 16 + m) * RS + kc * 32 + quad * 8]);
                // swapped operands -> transposed D: lane m = node, quad*4+r = out-col
                acc[ct] = __builtin_amdgcn_mfma_f32_16x16x32_bf16(b, a[kc], acc[ct], 0, 0, 0);
            }
        }
        int node = g0 + wid * 16 + m;
        if (node < N) {
#pragma unroll
            for (int ct = 0; ct < CT; ct++) {
                int colb = ct * 16 + quad * 4;          // 4 consecutive out-cols
                u16* op = outs[colb >> 7];
                int cc = colb & 127;
                float4v bq = *(const float4v*)&bsh[colb];
                ushort4 wv;
                wv.x = f2bf(acc[ct][0] + bq[0]);
                wv.y = f2bf(acc[ct][1] + bq[1]);
                wv.z = f2bf(acc[ct][2] + bq[2]);
                wv.w = f2bf(acc[ct][3] + bq[3]);
                *(ushort4*)(op + (size_t)node * 128 + cc) = wv;   // 8B store
            }
        }
    }
}

// ---------------- edge-parallel logit: wgt[slot][head] = exp(att . leaky(xl+xr+ee)) --------
// Massively parallel (SPW slots/wave): latency-tolerant home for the heavy per-edge VALU.
__global__ __launch_bounds__(256) void k_logit(
    const int* __restrict__ csr_src, const int* __restrict__ dst_csr,
    const u16* __restrict__ A_csr,
    const u16* __restrict__ xl, const u16* __restrict__ xr,
    const float* __restrict__ We, const float* __restrict__ att,
    float* __restrict__ wvec, int nslots) {
    int lane = threadIdx.x & 63;
    int w = __builtin_amdgcn_readfirstlane(blockIdx.x * 4 + (threadIdx.x >> 6));
    int j0 = w * SPW;
    if (j0 >= nslots) return;
    int jend = j0 + SPW; if (jend > nslots) jend = nslots;

    float2v we2[EDGE_D];
#pragma unroll
    for (int k = 0; k < EDGE_D; k++)
        we2[k] = (float2v){We[k * D_OUT + 2 * lane], We[k * D_OUT + 2 * lane + 1]};
    float a0 = att[2 * lane], a1 = att[2 * lane + 1];
    const u32* xl32 = (const u32*)xl;
    const u32* xr32 = (const u32*)xr;
    const float2v z0v = (float2v){0.f, 0.f};

    for (int j = j0; j < jend; j++) {
        int src = csr_src[j];                 // wave-uniform -> scalar load
        int dn  = dst_csr[j];
        u32 xw  = xl32[(size_t)src * 64 + lane];
        u32 xrw = xr32[(size_t)dn * 64 + lane];
        const uint4* ap = (const uint4*)(A_csr + (size_t)j * 16);   // j uniform -> s_load
        uint4 q0 = ap[0], q1 = ap[1];
        u32 dw[8] = {q0.x, q0.y, q0.z, q0.w, q1.x, q1.y, q1.z, q1.w};
        float2v eeA = (float2v){0.f, 0.f}, eeB = (float2v){0.f, 0.f};
#pragma unroll
        for (int k = 0; k < EDGE_D; k++) {
            u32 d = dw[k >> 1];
            float av = __uint_as_float((k & 1) ? (d & 0xffff0000u) : (d << 16));
            if ((k >> 1) & 1) eeB += we2[k] * av;
            else             eeA += we2[k] * av;
        }
        float2v xs  = (float2v){bf2f((u16)(xw & 0xffff)), bf2f((u16)(xw >> 16))};
        float2v xr2 = (float2v){bf2f((u16)(xrw & 0xffff)), bf2f((u16)(xrw >> 16))};
        float2v z = (xs + xr2) + (eeA + eeB);
        float2v lz = __builtin_elementwise_max(z, z0v) + __builtin_elementwise_min(z, z0v) * NEG_SLOPE;
        float p = lz[0] * a0 + lz[1] * a1;
        p = reduce16(p);
        float wgt = __expf(p);                // logits O(1): no max-subtraction
        if ((lane & 15) == 0) wvec[(size_t)j * 4 + (lane >> 4)] = wgt;
    }
}

// ---------------- fused GATv2 aggregate: light loop (precomputed wgt), deep gather ring ----
// POOL=true -> per-wave segment accumulation in registers, atomicAdd flush on graph boundary.
template <bool POOL>
__global__ __launch_bounds__(256) void k_gat(
    const int* __restrict__ csr_off, const int* __restrict__ csr_src,
    const float* __restrict__ wvec,
    const u16* __restrict__ xl, const u16* __restrict__ res,
    const float* __restrict__ ab,
    const float* __restrict__ lng, const float* __restrict__ lnb,
    u16* __restrict__ hout, const int* __restrict__ batch, float* __restrict__ gsum,
    int N, int npw) {
    int t = threadIdx.x;
    int wid = t >> 6, lane = t & 63;
    int wave = blockIdx.x * 4 + wid;
    int n0 = wave * npw;
    if (n0 >= N) return;
    int n1 = n0 + npw; if (n1 > N) n1 = N;

    float abv0 = ab[2 * lane], abv1 = ab[2 * lane + 1];
    float lg0 = lng[2 * lane], lg1 = lng[2 * lane + 1];
    float lb0 = lnb[2 * lane], lb1 = lnb[2 * lane + 1];
    int hd = lane >> 4;

    const u32* xl32 = (const u32*)xl;
    int wbeg = csr_off[n0];
    int wend = csr_off[n1];
    int nedge = wend - wbeg;

    float ps0 = 0.f, ps1 = 0.f;
    int gcur = POOL ? batch[n0] : -1;

    auto finish = [&](int n, float ssum, float2v acc2) {
        float inv = 1.f / ssum;
        float o0 = acc2[0] * inv + abv0;
        float o1 = acc2[1] * inv + abv1;
        o0 = (o0 > 0.f) ? o0 : (__expf(o0) - 1.f);   // ELU
        o1 = (o1 > 0.f) ? o1 : (__expf(o1) - 1.f);
        u32 rw = ((const u32*)res)[(size_t)n * 64 + lane];
        o0 += bf2f((u16)(rw & 0xffff));
        o1 += bf2f((u16)(rw >> 16));
        float sm = reduce64(o0 + o1);
        float mu = sm * (1.f / 128.f);
        float d0 = o0 - mu, d1 = o1 - mu;
        float vv = reduce64(d0 * d0 + d1 * d1);
        float rs = rsqrtf(vv * (1.f / 128.f) + LN_EPS);
        float h0 = d0 * rs * lg0 + lb0;
        float h1 = d1 * rs * lg1 + lb1;
        if (POOL) {
            int g = batch[n];
            if (g != gcur) {
                atomicAdd(gsum + (size_t)gcur * 128 + 2 * lane, ps0);
                atomicAdd(gsum + (size_t)gcur * 128 + 2 * lane + 1, ps1);
                ps0 = 0.f; ps1 = 0.f; gcur = g;
            }
            ps0 += h0; ps1 += h1;
        } else {
            ((u32*)hout)[(size_t)n * 64 + lane] = (u32)f2bf(h0) | ((u32)f2bf(h1) << 16);
        }
    };

    if (nedge <= 64) {
        // ---- fast path: src indices preloaded; xl ring depth 8, wgt ring depth 4 ----
        int last = nedge - 1;
        int sv = csr_src[wbeg + ((lane < nedge) ? lane : last)];
        u32 xw[8];
        float wg[4];
#pragma unroll
        for (int r = 0; r < 8; r++) {
            int jr = (r <= last) ? r : last;
            int fr = __builtin_amdgcn_readlane(sv, jr);
            xw[r] = xl32[(size_t)fr * 64 + lane];
        }
#pragma unroll
        for (int r = 0; r < 4; r++) {
            int jr = (r <= last) ? r : last;
            wg[r] = wvec[(size_t)(wbeg + jr) * 4 + hd];
        }

        int i = wbeg;
        for (int n = n0; n < n1; n++) {
            int end = csr_off[n + 1];
            float ssum = 0.f;
            float2v acc2 = (float2v){0.f, 0.f};
            for (; i < end; i++) {
                int j8 = i + 8 - wbeg; if (j8 > last) j8 = last;
                int f8 = __builtin_amdgcn_readlane(sv, j8);
                u32 xwN = xl32[(size_t)f8 * 64 + lane];
                int j4 = i + 4 - wbeg; if (j4 > last) j4 = last;
                float wgN = wvec[(size_t)(wbeg + j4) * 4 + hd];

                float2v xs = (float2v){bf2f((u16)(xw[0] & 0xffff)), bf2f((u16)(xw[0] >> 16))};
                ssum += wg[0];
                acc2 += xs * wg[0];
#pragma unroll
                for (int r = 0; r < 7; r++) xw[r] = xw[r + 1];
                xw[7] = xwN;
#pragma unroll
                for (int r = 0; r < 3; r++) wg[r] = wg[r + 1];
                wg[3] = wgN;
            }
            finish(n, ssum, acc2);
        }
    } else {
        // ---- generic fallback (nedge > 64; rare at npw=4) ----
        int cl = wend - 1;
        int f = csr_src[wbeg];
        u32 xw = xl32[(size_t)f * 64 + lane];
        float wg = wvec[(size_t)wbeg * 4 + hd];
        int i = wbeg;
        for (int n = n0; n < n1; n++) {
            int end = csr_off[n + 1];
            float ssum = 0.f;
            float2v acc2 = (float2v){0.f, 0.f};
            for (; i < end; i++) {
                u32 xwc = xw; float wgc = wg;
                int ip = (i + 1 < wend) ? i + 1 : cl;
                f = csr_src[ip];
                xw = xl32[(size_t)f * 64 + lane];
                wg = wvec[(size_t)ip * 4 + hd];
                float2v xs = (float2v){bf2f((u16)(xwc & 0xffff)), bf2f((u16)(xwc >> 16))};
                ssum += wgc;
                acc2 += xs * wgc;
            }
            finish(n, ssum, acc2);
        }
    }

    if (POOL) {
        atomicAdd(gsum + (size_t)gcur * 128 + 2 * lane, ps0);
        atomicAdd(gsum + (size_t)gcur * 128 + 2 * lane + 1, ps1);
    }
}

// ---------------- readout MLP on pre-pooled sums ----------------
__global__ __launch_bounds__(128) void k_read(
    const float* __restrict__ gsum, const int* __restrict__ goff,
    const float* __restrict__ Wd1, const float* __restrict__ bd1,
    const float* __restrict__ Wd2, const float* __restrict__ bd2,
    float* __restrict__ out, int G) {
    __shared__ float psh[128];
    __shared__ float rsh[2][64];
    int g = blockIdx.x;
    int t = threadIdx.x;
    int cnt = goff[g + 1] - goff[g];
    float inv = 1.f / fmaxf((float)cnt, 1.f);
    psh[t] = gsum[(size_t)g * 128 + t] * inv;
    __syncthreads();
    int j = t & 63, hw = t >> 6;
    float acc = (hw == 0) ? bd1[j] : 0.f;
    int k0 = hw * 64;
    for (int k = k0; k < k0 + 64; k++)
        acc += psh[k] * Wd1[k * 64 + j];
    rsh[hw][j] = acc;
    __syncthreads();
    if (t < 64) {
        float a = fmaxf(rsh[0][t] + rsh[1][t], 0.f);
        float v = a * Wd2[t];
#pragma unroll
        for (int mk = 1; mk < 64; mk <<= 1) v += __shfl_xor(v, mk, 64);
        if (t == 0) out[g] = v + bd2[0];
    }
}

extern "C" void kernel_launch(void* const* d_in, const int* in_sizes, int n_in,
                              void* d_out, int out_size, void* d_ws, size_t ws_size,
                              hipStream_t stream) {
    const float* x     = (const float*)d_in[0];
    const int*   eidx  = (const int*)d_in[1];
    const float* eattr = (const float*)d_in[2];
    const int*   batch = (const int*)d_in[3];
    const float* Wl1 = (const float*)d_in[4],  *bl1 = (const float*)d_in[5];
    const float* Wr1 = (const float*)d_in[6],  *br1 = (const float*)d_in[7];
    const float* We1 = (const float*)d_in[8],  *att1 = (const float*)d_in[9],  *ab1 = (const float*)d_in[10];
    const float* lng1 = (const float*)d_in[11], *lnb1 = (const float*)d_in[12];
    const float* Wres = (const float*)d_in[13], *bres = (const float*)d_in[14];
    const float* Wl2 = (const float*)d_in[15], *bl2 = (const float*)d_in[16];
    const float* Wr2 = (const float*)d_in[17], *br2 = (const float*)d_in[18];
    const float* We2 = (const float*)d_in[19], *att2 = (const float*)d_in[20], *ab2 = (const float*)d_in[21];
    const float* lng2 = (const float*)d_in[22], *lnb2 = (const float*)d_in[23];
    const float* Wd1 = (const float*)d_in[24], *bd1 = (const float*)d_in[25];
    const float* Wd2 = (const float*)d_in[26], *bd2 = (const float*)d_in[27];

    int N = in_sizes[0] / NODE_D;
    int E = in_sizes[1] / 2;
    int G = out_size;
    int EN = E + N;                         // slots incl. self loops
    const int* src = eidx;
    const int* dst = eidx + E;

    char* w = (char*)d_ws;
    auto alloc = [&](size_t bytes) -> char* {
        char* p = w;
        w += (bytes + 255) & ~(size_t)255;
        return p;
    };
    int NB = (N + SCAN_CHUNK - 1) / SCAN_CHUNK;
    // ---- persistent buffers ----
    int*   csr_off  = (int*)alloc((size_t)(N + 1) * 4);
    int*   csr_src  = (int*)alloc((size_t)EN * 4);
    int*   dst_csr  = (int*)alloc((size_t)EN * 4);
    u16*   A_csr    = (u16*)alloc((size_t)(EN + 64) * 16 * 2);
    float* wvec     = (float*)alloc((size_t)EN * 4 * 4);   // per-slot, per-head weight
    u16*   xb       = (u16*)alloc((size_t)N * 64 * 2);     // bf16 x, padded 38->64
    u16*   xlb      = (u16*)alloc((size_t)N * D_OUT * 2);
    u16*   xrb      = (u16*)alloc((size_t)N * D_OUT * 2);
    u16*   resb     = (u16*)alloc((size_t)N * D_OUT * 2);  // res1
    u16*   hb       = (u16*)alloc((size_t)N * D_OUT * 2);
    int*   goff     = (int*)alloc((size_t)(G + 1) * 4);
    // ---- zeroed scratch (deg/fill/gsum adjacent -> one memset) ----
    size_t szN = ((size_t)N * 4 + 255) & ~(size_t)255;
    size_t szG = ((size_t)G * 128 * 4 + 255) & ~(size_t)255;
    char*  zp   = alloc(2 * szN + szG);
    int*   deg  = (int*)zp;
    int*   fill = (int*)(zp + szN);
    float* gsum = (float*)(zp + 2 * szN);
    int*   bsum = (int*)alloc((size_t)(NB + 1) * 4);
    int*   boff = (int*)alloc((size_t)(NB + 1) * 4);

    hipMemsetAsync(zp, 0, 2 * szN + szG, stream);

    // ---- degree count + graph offsets + x cast (fused) ----
    int mx = (E > N * 32) ? E : N * 32;
    k_pre<<<(mx + 255) / 256, 256, 0, stream>>>(dst, E, deg, batch, N, G, goff, x, xb);

    // ---- CSR with self-loops folded in; A rows written at scatter time ----
    k_scan1<<<NB, 256, 0, stream>>>(deg, N, 1, bsum);
    k_scan2<<<1, 256, 0, stream>>>(bsum, NB, boff);
    k_scan3<<<NB, 256, 0, stream>>>(deg, N, 1, boff, NB, csr_off);
    k_fill<<<(E + 255) / 256, 256, 0, stream>>>(src, dst, eattr, E, csr_off, fill, csr_src, dst_csr, A_csr);
    k_self<<<(N + 3) / 4, 256, 0, stream>>>(csr_off, N, csr_src, dst_csr, A_csr);

    // ---- launch geometry ----
    int npw = 4;
    int gblocks = (N + npw * 4 - 1) / (npw * 4);
    int lwaves = (EN + SPW - 1) / SPW;
    int lblocks = (lwaves + 3) / 4;

    // ---- block 1 ----
    k_tf_mfma<64, 24, NODE_D, true><<<512, 256, 0, stream>>>(
        xb, Wl1, bl1, Wr1, br1, Wres, bres, xlb, xrb, resb, N);
    k_logit<<<lblocks, 256, 0, stream>>>(csr_src, dst_csr, A_csr, xlb, xrb, We1, att1, wvec, EN);
    k_gat<false><<<gblocks, 256, 0, stream>>>(csr_off, csr_src, wvec,
                                              xlb, resb, ab1, lng1, lnb1,
                                              hb, nullptr, nullptr, N, npw);

    // ---- block 2 (pool fused into epilogue; segment-accumulated atomics) ----
    k_tf_mfma<128, 16, 128, true><<<512, 256, 0, stream>>>(
        hb, Wl2, bl2, Wr2, br2, Wr2, br2, xlb, xrb, xrb, N);
    k_logit<<<lblocks, 256, 0, stream>>>(csr_src, dst_csr, A_csr, xlb, xrb, We2, att2, wvec, EN);
    k_gat<true><<<gblocks, 256, 0, stream>>>(csr_off, csr_src, wvec,
                                             xlb, hb, ab2, lng2, lnb2,
                                             (u16*)nullptr, batch, gsum, N, npw);

    // ---- readout MLP on pooled sums ----
    k_read<<<G, 128, 0, stream>>>(gsum, goff, Wd1, bd1, Wd2, bd2, (float*)d_out, G);
}

// Round 10
// 531.177 us; speedup vs baseline: 1.0599x; 1.0599x over previous
//
#include <hip/hip_runtime.h>

typedef unsigned short u16;
typedef unsigned int   u32;
typedef __attribute__((ext_vector_type(8))) short short8;
typedef __attribute__((ext_vector_type(4))) float float4v;
typedef __attribute__((ext_vector_type(2))) float float2v;
typedef __attribute__((ext_vector_type(4), aligned(4))) float float4u;   // dword-aligned vec load

#define NODE_D   38
#define EDGE_D   13
#define D_OUT    128
#define NEG_SLOPE 0.2f
#define LN_EPS   1e-5f

__device__ __forceinline__ float bf2f(u16 v) { return __uint_as_float(((u32)v) << 16); }
__device__ __forceinline__ u16 f2bf(float f) {
    u32 u = __float_as_uint(f);
    u += 0x7fffu + ((u >> 16) & 1u);   // round-to-nearest-even
    return (u16)(u >> 16);
}

// ---- DPP 16-lane all-reduce: 4 VALU adds, no LDS pipe, no lgkm waits ----
template <int CTRL>
__device__ __forceinline__ float dpp_radd(float x) {
    int t = __builtin_amdgcn_update_dpp(0, __float_as_int(x), CTRL, 0xf, 0xf, true);
    return x + __int_as_float(t);
}
__device__ __forceinline__ float reduce16(float p) {
    p = dpp_radd<0xB1>(p);    // quad_perm [1,0,3,2]  : xor 1
    p = dpp_radd<0x4E>(p);    // quad_perm [2,3,0,1]  : xor 2
    p = dpp_radd<0x124>(p);   // row_ror:4
    p = dpp_radd<0x128>(p);   // row_ror:8 -> all 16 lanes hold group sum
    return p;
}
__device__ __forceinline__ float reduce64(float v) {
    v = reduce16(v);
    v += __shfl_xor(v, 16, 64);
    v += __shfl_xor(v, 32, 64);
    return v;
}

// ---------------- fused: degree count + graph offsets + x->bf16 cast ----------------
__global__ void k_pre(const int* __restrict__ dst, int E, int* __restrict__ deg,
                      const int* __restrict__ batch, int N, int G, int* __restrict__ goff,
                      const float* __restrict__ x, u16* __restrict__ xb) {
    int i = blockIdx.x * blockDim.x + threadIdx.x;
    if (i < E) atomicAdd(deg + dst[i], 1);
    if (i < N) {
        int b = batch[i];
        int prev = (i == 0) ? -1 : batch[i - 1];
        for (int g = prev + 1; g <= b; g++) goff[g] = i;
        if (i == N - 1)
            for (int g = b + 1; g <= G; g++) goff[g] = N;
    }
    if (i < N * 32) {   // x (f32, 38 wide) -> bf16 rows padded to 64
        int n = i >> 5, kk = (i & 31) * 2;
        float f0 = 0.f, f1 = 0.f;
        if (kk < NODE_D) {   // NODE_D even -> pair never straddles row end; 8B-aligned
            float2v v = *(const float2v*)(x + (size_t)n * NODE_D + kk);
            f0 = v[0]; f1 = v[1];
        }
        ((u32*)xb)[(size_t)n * 32 + (i & 31)] = (u32)f2bf(f0) | ((u32)f2bf(f1) << 16);
    }
}

// ---------------- single-launch scan (all chunk-blocks co-resident; spin barrier) ----------
// slot count per node = deg + 1 (self loop). Requires nb <= 256 (N <= 256*1024).
#define SCAN_CHUNK 1024
__global__ __launch_bounds__(256) void k_scan(
    const int* __restrict__ cnt, int N, int nb,
    int* __restrict__ bsum, int* __restrict__ done, int* __restrict__ off) {
    __shared__ int wtot[4];
    __shared__ int sh[256];
    int base = blockIdx.x * SCAN_CHUNK;
    int t = threadIdx.x, lane = t & 63, w = t >> 6;
    int v[4]; int s = 0;
#pragma unroll
    for (int i = 0; i < 4; i++) { int idx = base + t * 4 + i; v[i] = (idx < N) ? cnt[idx] + 1 : 0; s += v[i]; }
    int inc = s;
#pragma unroll
    for (int ofs = 1; ofs < 64; ofs <<= 1) {
        int x = __shfl_up(inc, ofs, 64);
        if (lane >= ofs) inc += x;
    }
    if (lane == 63) wtot[w] = inc;
    __syncthreads();
    int wofs = 0;
    for (int i = 0; i < w; i++) wofs += wtot[i];
    int btot = wtot[0] + wtot[1] + wtot[2] + wtot[3];
    if (t == 0) {
        __hip_atomic_store(&bsum[blockIdx.x], btot, __ATOMIC_RELEASE, __HIP_MEMORY_SCOPE_AGENT);
        atomicAdd(done, 1);                                  // device-scope arrive
        while (__hip_atomic_load(done, __ATOMIC_ACQUIRE, __HIP_MEMORY_SCOPE_AGENT) < nb) {}
    }
    __syncthreads();
    // exclusive block offset (agent-scope loads: cross-XCD safe)
    int val = (t < blockIdx.x) ? __hip_atomic_load(&bsum[t], __ATOMIC_ACQUIRE, __HIP_MEMORY_SCOPE_AGENT) : 0;
    sh[t] = val; __syncthreads();
    for (int ofs = 128; ofs > 0; ofs >>= 1) {
        if (t < ofs) sh[t] += sh[t + ofs];
        __syncthreads();
    }
    int boffb = sh[0];
    int run = boffb + wofs + (inc - s);
#pragma unroll
    for (int i = 0; i < 4; i++) {
        int idx = base + t * 4 + i;
        if (idx < N) off[idx] = run;
        run += v[i];
    }
    if (blockIdx.x == nb - 1 && t == 0) off[N] = boffb + btot;
}

// ---------------- CSR fill: scatter src AND the bf16 A-row (16-wide, padded) ----------------
__global__ void k_fill(const int* __restrict__ src, const int* __restrict__ dst,
                       const float* __restrict__ eattr, int E,
                       const int* __restrict__ csr_off, int* __restrict__ fill,
                       int* __restrict__ csr_src, u16* __restrict__ A) {
    int e = blockIdx.x * blockDim.x + threadIdx.x;
    if (e >= E) return;
    int d = dst[e];
    int pos = csr_off[d] + atomicAdd(fill + d, 1);
    csr_src[pos] = src[e];
    const float* ep = eattr + (size_t)e * EDGE_D;
    float4u v0 = *(const float4u*)(ep);          // dwordx4, dword-aligned
    float4u v1 = *(const float4u*)(ep + 4);
    float4u v2 = *(const float4u*)(ep + 8);
    float   v3 = ep[12];
    u16 row[16];
#pragma unroll
    for (int k = 0; k < 4; k++) { row[k] = f2bf(v0[k]); row[4 + k] = f2bf(v1[k]); row[8 + k] = f2bf(v2[k]); }
    row[12] = f2bf(v3);
#pragma unroll
    for (int k = EDGE_D; k < 16; k++) row[k] = 0;
    uint4* rp = (uint4*)(A + (size_t)pos * 16);
    rp[0] = (uint4){(u32)row[0] | ((u32)row[1] << 16), (u32)row[2] | ((u32)row[3] << 16),
                    (u32)row[4] | ((u32)row[5] << 16), (u32)row[6] | ((u32)row[7] << 16)};
    rp[1] = (uint4){(u32)row[8] | ((u32)row[9] << 16), (u32)row[10] | ((u32)row[11] << 16),
                    (u32)row[12] | ((u32)row[13] << 16), (u32)row[14] | ((u32)row[15] << 16)};
}

// ---------------- self rows: one WAVE per node, coalesced 4-row x 16-ch lanes ----------------
__global__ __launch_bounds__(256) void k_self(const int* __restrict__ csr_off, int N,
                                              int* __restrict__ csr_src, u16* __restrict__ A) {
    int wave = blockIdx.x * 4 + (threadIdx.x >> 6);
    if (wave >= N) return;
    int lane = threadIdx.x & 63;
    int r = lane >> 4, k = lane & 15;
    int b = csr_off[wave], e2 = csr_off[wave + 1] - 1;   // e2 = self slot
    float s = 0.f;
    for (int j = b + r; j < e2; j += 4)                  // lanes cover 4 rows x 16 ch: 128B/iter
        s += bf2f(A[(size_t)j * 16 + k]);
    s += __shfl_xor(s, 16, 64);
    s += __shfl_xor(s, 32, 64);
    if (lane < 16) {
        u16 v = (k < EDGE_D) ? f2bf(s / fmaxf((float)(e2 - b), 1.f)) : (u16)0;
        A[(size_t)e2 * 16 + k] = v;
        if (k == 0) csr_src[e2] = wave;
    }
}

// ---------------- MFMA multi-output transform (transposed store: 8B ushort4 per lane) ------
template <int KPAD, int CT, int KREAL, bool IN_BF16>
__global__ __launch_bounds__(256) void k_tf_mfma(
    const void* __restrict__ in_v,
    const float* __restrict__ W0, const float* __restrict__ b0,
    const float* __restrict__ W1, const float* __restrict__ b1,
    const float* __restrict__ W2, const float* __restrict__ b2,
    u16* __restrict__ o0, u16* __restrict__ o1, u16* __restrict__ o2,
    int N) {
    constexpr int RS = KPAD + 8;
    __shared__ u16 Bsw[CT * 16 * RS];
    __shared__ float bsh[CT * 16];
    const float* Ws[3] = {W0, W1, W2};
    const float* bs[3] = {b0, b1, b2};
    u16* outs[3] = {o0, o1, o2};
    int t = threadIdx.x;
    for (int i = t; i < CT * 16 * KPAD; i += 256) {
        int c = i / KPAD, k = i - c * KPAD;
        float v = (k < KREAL) ? Ws[c >> 7][(size_t)k * 128 + (c & 127)] : 0.f;
        Bsw[c * RS + k] = f2bf(v);
    }
    for (int i = t; i < CT * 16; i += 256) bsh[i] = bs[i >> 7][i & 127];
    __syncthreads();

    int wid = t >> 6, lane = t & 63;
    int quad = lane >> 4, m = lane & 15;

    for (int g0 = blockIdx.x * 64; g0 < N; g0 += gridDim.x * 64) {
        int na = g0 + wid * 16 + m;
        if (na > N - 1) na = N - 1;
        short8 a[KPAD / 32];
        if (IN_BF16) {
            const u16* in = (const u16*)in_v;
#pragma unroll
            for (int kc = 0; kc < KPAD / 32; kc++)
                a[kc] = *(const short8*)(in + (size_t)na * KPAD + kc * 32 + quad * 8);
        } else {
            const float* in = (const float*)in_v;
#pragma unroll
            for (int kc = 0; kc < KPAD / 32; kc++)
#pragma unroll
                for (int j = 0; j < 8; j++) {
                    int k = kc * 32 + quad * 8 + j;
                    float v = (k < KREAL) ? in[(size_t)na * KREAL + k] : 0.f;
                    a[kc][j] = (short)f2bf(v);
                }
        }
        float4v acc[CT];
#pragma unroll
        for (int ct = 0; ct < CT; ct++) acc[ct] = (float4v){0.f, 0.f, 0.f, 0.f};
#pragma unroll
        for (int ct = 0; ct < CT; ct++) {
#pragma unroll
            for (int kc = 0; kc < KPAD / 32; kc++) {
                short8 b = *(const short8*)(&Bsw[(ct * 16 + m) * RS + kc * 32 + quad * 8]);
                // swapped operands -> transposed D: lane m = node, quad*4+r = out-col
                acc[ct] = __builtin_amdgcn_mfma_f32_16x16x32_bf16(b, a[kc], acc[ct], 0, 0, 0);
            }
        }
        int node = g0 + wid * 16 + m;
        if (node < N) {
#pragma unroll
            for (int ct = 0; ct < CT; ct++) {
                int colb = ct * 16 + quad * 4;          // 4 consecutive out-cols
                u16* op = outs[colb >> 7];
                int cc = colb & 127;
                float4v bq = *(const float4v*)&bsh[colb];
                ushort4 wv;
                wv.x = f2bf(acc[ct][0] + bq[0]);
                wv.y = f2bf(acc[ct][1] + bq[1]);
                wv.z = f2bf(acc[ct][2] + bq[2]);
                wv.w = f2bf(acc[ct][3] + bq[3]);
                *(ushort4*)(op + (size_t)node * 128 + cc) = wv;   // 8B store
            }
        }
    }
}

// ---------------- fused GATv2 block: depth-4 xl gather pipeline, scalar A-row loads --------
// POOL=true -> per-wave segment accumulation in registers, atomicAdd flush on graph boundary.
template <bool POOL>
__global__ __launch_bounds__(256) void k_gat(
    const int* __restrict__ csr_off, const int* __restrict__ csr_src,
    const u16* __restrict__ A_csr,
    const u16* __restrict__ xl, const u16* __restrict__ xr,
    const u16* __restrict__ res, const float* __restrict__ We,
    const float* __restrict__ att, const float* __restrict__ ab,
    const float* __restrict__ lng, const float* __restrict__ lnb,
    u16* __restrict__ hout, const int* __restrict__ batch, float* __restrict__ gsum,
    int N, int npw) {
    int t = threadIdx.x;
    int wid = t >> 6, lane = t & 63;
    int wave = blockIdx.x * 4 + wid;
    int n0 = wave * npw;
    if (n0 >= N) return;
    int n1 = n0 + npw; if (n1 > N) n1 = N;

    // ---- node-invariant preamble (once per wave) ----
    float2v we2[EDGE_D];
#pragma unroll
    for (int k = 0; k < EDGE_D; k++)
        we2[k] = (float2v){We[k * D_OUT + 2 * lane], We[k * D_OUT + 2 * lane + 1]};
    float a0 = att[2 * lane], a1 = att[2 * lane + 1];
    float abv0 = ab[2 * lane], abv1 = ab[2 * lane + 1];
    float lg0 = lng[2 * lane], lg1 = lng[2 * lane + 1];
    float lb0 = lnb[2 * lane], lb1 = lnb[2 * lane + 1];

    const u32* xl32 = (const u32*)xl;
    const u32* xr32 = (const u32*)xr;
    int wbeg = csr_off[n0];
    int wend = csr_off[n1];
    int nedge = wend - wbeg;

    // ---- pooled-segment registers (POOL path) ----
    float ps0 = 0.f, ps1 = 0.f;
    int gcur = POOL ? batch[n0] : -1;

    auto finish = [&](int n, float ssum, float2v acc2) {
        float inv = 1.f / ssum;
        float o0 = acc2[0] * inv + abv0;
        float o1 = acc2[1] * inv + abv1;
        o0 = (o0 > 0.f) ? o0 : (__expf(o0) - 1.f);   // ELU
        o1 = (o1 > 0.f) ? o1 : (__expf(o1) - 1.f);
        u32 rw = ((const u32*)res)[(size_t)n * 64 + lane];
        o0 += bf2f((u16)(rw & 0xffff));
        o1 += bf2f((u16)(rw >> 16));
        // LN via E[x], E[x^2]: the two reduce64 chains are independent -> ILP overlap
        float s1 = reduce64(o0 + o1);
        float s2 = reduce64(o0 * o0 + o1 * o1);
        float mu = s1 * (1.f / 128.f);
        float var = s2 * (1.f / 128.f) - mu * mu;
        float rs = rsqrtf(var + LN_EPS);
        float h0 = (o0 - mu) * rs * lg0 + lb0;
        float h1 = (o1 - mu) * rs * lg1 + lb1;
        if (POOL) {
            int g = batch[n];                         // wave-uniform (n is wave-uniform)
            if (g != gcur) {                          // flush previous segment
                atomicAdd(gsum + (size_t)gcur * 128 + 2 * lane, ps0);
                atomicAdd(gsum + (size_t)gcur * 128 + 2 * lane + 1, ps1);
                ps0 = 0.f; ps1 = 0.f; gcur = g;
            }
            ps0 += h0; ps1 += h1;
        } else {
            ((u32*)hout)[(size_t)n * 64 + lane] = (u32)f2bf(h0) | ((u32)f2bf(h1) << 16);
        }
    };

    const float2v z0v = (float2v){0.f, 0.f};

    if (nedge <= 64) {
        // ---- fast path: wave src indices preloaded; xl gather ring depth 4 ----
        int last = nedge - 1;
        int sv = csr_src[wbeg + ((lane < nedge) ? lane : last)];
        int f0 = __builtin_amdgcn_readlane(sv, 0);
        int f1 = __builtin_amdgcn_readlane(sv, (1 <= last) ? 1 : last);
        int f2 = __builtin_amdgcn_readlane(sv, (2 <= last) ? 2 : last);
        int f3 = __builtin_amdgcn_readlane(sv, (3 <= last) ? 3 : last);
        u32 xw0 = xl32[(size_t)f0 * 64 + lane];   // 4 row-gathers in flight per wave
        u32 xw1 = xl32[(size_t)f1 * 64 + lane];
        u32 xw2 = xl32[(size_t)f2 * 64 + lane];
        u32 xw3 = xl32[(size_t)f3 * 64 + lane];
        // A-row: wave-uniform -> force scalar (SMEM) load path
        int wbu = __builtin_amdgcn_readfirstlane(wbeg);
        const uint4* ap = (const uint4*)(A_csr + (size_t)wbu * 16);
        uint4 aq0 = ap[0], aq1 = ap[1];

        int i = wbeg;
        for (int n = n0; n < n1; n++) {
            int end = csr_off[n + 1];
            u32 xrw = xr32[(size_t)n * 64 + lane];
            float2v xr2 = (float2v){bf2f((u16)(xrw & 0xffff)), bf2f((u16)(xrw >> 16))};
            float ssum = 0.f;
            float2v acc2 = (float2v){0.f, 0.f};
            for (; i < end; i++) {
                // prefetch: xl four ahead, A one ahead (scalar-indexed)
                int j4 = i + 4 - wbeg; if (j4 > last) j4 = last;
                int f4 = __builtin_amdgcn_readlane(sv, j4);
                u32 xwN = xl32[(size_t)f4 * 64 + lane];
                int j1n = i + 1 - wbeg; if (j1n > last) j1n = last;
                int ipu = __builtin_amdgcn_readfirstlane(wbeg + j1n);
                const uint4* apn = (const uint4*)(A_csr + (size_t)ipu * 16);
                uint4 an0 = apn[0], an1 = apn[1];

                u32 dw[8] = {aq0.x, aq0.y, aq0.z, aq0.w, aq1.x, aq1.y, aq1.z, aq1.w};
                float2v eeA = (float2v){0.f, 0.f}, eeB = (float2v){0.f, 0.f};
#pragma unroll
                for (int k = 0; k < EDGE_D; k++) {
                    u32 d = dw[k >> 1];
                    float av = __uint_as_float((k & 1) ? (d & 0xffff0000u) : (d << 16));
                    if ((k >> 1) & 1) eeB += we2[k] * av;   // two interleaved fma chains
                    else             eeA += we2[k] * av;
                }
                float2v xs = (float2v){bf2f((u16)(xw0 & 0xffff)), bf2f((u16)(xw0 >> 16))};
                float2v z = (xs + xr2) + (eeA + eeB);
                float2v lz = __builtin_elementwise_max(z, z0v) + __builtin_elementwise_min(z, z0v) * NEG_SLOPE;
                float p = lz[0] * a0 + lz[1] * a1;
                p = reduce16(p);                    // DPP, VALU-only
                float wgt = __expf(p);              // logits are O(1): no max-subtraction
                ssum += wgt;
                acc2 += xs * wgt;
                xw0 = xw1; xw1 = xw2; xw2 = xw3; xw3 = xwN;
                aq0 = an0; aq1 = an1;
            }
            finish(n, ssum, acc2);
        }
    } else {
        // ---- generic fallback (nedge > 64; rare at npw=4) ----
        int cl = wend - 1;
        int f = csr_src[wbeg];
        u32 xw = xl32[(size_t)f * 64 + lane];
        int wbu = __builtin_amdgcn_readfirstlane(wbeg);
        const uint4* ap = (const uint4*)(A_csr + (size_t)wbu * 16);
        uint4 aq0 = ap[0], aq1 = ap[1];
        int i = wbeg;
        for (int n = n0; n < n1; n++) {
            int end = csr_off[n + 1];
            u32 xrw = xr32[(size_t)n * 64 + lane];
            float2v xr2 = (float2v){bf2f((u16)(xrw & 0xffff)), bf2f((u16)(xrw >> 16))};
            float ssum = 0.f;
            float2v acc2 = (float2v){0.f, 0.f};
            for (; i < end; i++) {
                u32 xwc = xw; uint4 q0 = aq0, q1 = aq1;
                int ip = (i + 1 < wend) ? i + 1 : cl;
                f = csr_src[ip];
                xw = xl32[(size_t)f * 64 + lane];
                int ipu = __builtin_amdgcn_readfirstlane(ip);
                const uint4* ap2 = (const uint4*)(A_csr + (size_t)ipu * 16);
                aq0 = ap2[0]; aq1 = ap2[1];
                u32 dw[8] = {q0.x, q0.y, q0.z, q0.w, q1.x, q1.y, q1.z, q1.w};
                float2v eeA = (float2v){0.f, 0.f}, eeB = (float2v){0.f, 0.f};
#pragma unroll
                for (int k = 0; k < EDGE_D; k++) {
                    u32 d = dw[k >> 1];
                    float av = __uint_as_float((k & 1) ? (d & 0xffff0000u) : (d << 16));
                    if ((k >> 1) & 1) eeB += we2[k] * av;
                    else             eeA += we2[k] * av;
                }
                float2v xs = (float2v){bf2f((u16)(xwc & 0xffff)), bf2f((u16)(xwc >> 16))};
                float2v z = (xs + xr2) + (eeA + eeB);
                float2v lz = __builtin_elementwise_max(z, z0v) + __builtin_elementwise_min(z, z0v) * NEG_SLOPE;
                float p = lz[0] * a0 + lz[1] * a1;
                p = reduce16(p);
                float wgt = __expf(p);
                ssum += wgt;
                acc2 += xs * wgt;
            }
            finish(n, ssum, acc2);
        }
    }

    // ---- final segment flush (POOL path) ----
    if (POOL) {
        atomicAdd(gsum + (size_t)gcur * 128 + 2 * lane, ps0);
        atomicAdd(gsum + (size_t)gcur * 128 + 2 * lane + 1, ps1);
    }
}

// ---------------- readout MLP on pre-pooled sums ----------------
__global__ __launch_bounds__(128) void k_read(
    const float* __restrict__ gsum, const int* __restrict__ goff,
    const float* __restrict__ Wd1, const float* __restrict__ bd1,
    const float* __restrict__ Wd2, const float* __restrict__ bd2,
    float* __restrict__ out, int G) {
    __shared__ float psh[128];
    __shared__ float rsh[2][64];
    int g = blockIdx.x;
    int t = threadIdx.x;
    int cnt = goff[g + 1] - goff[g];
    float inv = 1.f / fmaxf((float)cnt, 1.f);
    psh[t] = gsum[(size_t)g * 128 + t] * inv;
    __syncthreads();
    int j = t & 63, hw = t >> 6;
    float acc = (hw == 0) ? bd1[j] : 0.f;
    int k0 = hw * 64;
    for (int k = k0; k < k0 + 64; k++)
        acc += psh[k] * Wd1[k * 64 + j];
    rsh[hw][j] = acc;
    __syncthreads();
    if (t < 64) {
        float a = fmaxf(rsh[0][t] + rsh[1][t], 0.f);
        float v = a * Wd2[t];
#pragma unroll
        for (int mk = 1; mk < 64; mk <<= 1) v += __shfl_xor(v, mk, 64);
        if (t == 0) out[g] = v + bd2[0];
    }
}

extern "C" void kernel_launch(void* const* d_in, const int* in_sizes, int n_in,
                              void* d_out, int out_size, void* d_ws, size_t ws_size,
                              hipStream_t stream) {
    const float* x     = (const float*)d_in[0];
    const int*   eidx  = (const int*)d_in[1];
    const float* eattr = (const float*)d_in[2];
    const int*   batch = (const int*)d_in[3];
    const float* Wl1 = (const float*)d_in[4],  *bl1 = (const float*)d_in[5];
    const float* Wr1 = (const float*)d_in[6],  *br1 = (const float*)d_in[7];
    const float* We1 = (const float*)d_in[8],  *att1 = (const float*)d_in[9],  *ab1 = (const float*)d_in[10];
    const float* lng1 = (const float*)d_in[11], *lnb1 = (const float*)d_in[12];
    const float* Wres = (const float*)d_in[13], *bres = (const float*)d_in[14];
    const float* Wl2 = (const float*)d_in[15], *bl2 = (const float*)d_in[16];
    const float* Wr2 = (const float*)d_in[17], *br2 = (const float*)d_in[18];
    const float* We2 = (const float*)d_in[19], *att2 = (const float*)d_in[20], *ab2 = (const float*)d_in[21];
    const float* lng2 = (const float*)d_in[22], *lnb2 = (const float*)d_in[23];
    const float* Wd1 = (const float*)d_in[24], *bd1 = (const float*)d_in[25];
    const float* Wd2 = (const float*)d_in[26], *bd2 = (const float*)d_in[27];

    int N = in_sizes[0] / NODE_D;
    int E = in_sizes[1] / 2;
    int G = out_size;
    int EN = E + N;
    const int* src = eidx;
    const int* dst = eidx + E;

    char* w = (char*)d_ws;
    auto alloc = [&](size_t bytes) -> char* {
        char* p = w;
        w += (bytes + 255) & ~(size_t)255;
        return p;
    };
    int NB = (N + SCAN_CHUNK - 1) / SCAN_CHUNK;
    // ---- persistent buffers ----
    int*   csr_off  = (int*)alloc((size_t)(N + 1) * 4);
    int*   csr_src  = (int*)alloc((size_t)EN * 4);
    u16*   A_csr    = (u16*)alloc((size_t)(EN + 64) * 16 * 2);
    u16*   xb       = (u16*)alloc((size_t)N * 64 * 2);     // bf16 x, padded 38->64
    u16*   xlb      = (u16*)alloc((size_t)N * D_OUT * 2);
    u16*   xrb      = (u16*)alloc((size_t)N * D_OUT * 2);
    u16*   resb     = (u16*)alloc((size_t)N * D_OUT * 2);  // res1
    u16*   hb       = (u16*)alloc((size_t)N * D_OUT * 2);
    int*   goff     = (int*)alloc((size_t)(G + 1) * 4);
    // ---- zeroed scratch (deg/fill/gsum/done adjacent -> one memset) ----
    size_t szN = ((size_t)N * 4 + 255) & ~(size_t)255;
    size_t szG = ((size_t)G * 128 * 4 + 255) & ~(size_t)255;
    char*  zp   = alloc(2 * szN + szG + 256);
    int*   deg  = (int*)zp;
    int*   fill = (int*)(zp + szN);
    float* gsum = (float*)(zp + 2 * szN);
    int*   done = (int*)(zp + 2 * szN + szG);
    int*   bsum = (int*)alloc((size_t)(NB + 1) * 4);

    hipMemsetAsync(zp, 0, 2 * szN + szG + 256, stream);

    // ---- degree count + graph offsets + x cast (fused) ----
    int mx = (E > N * 32) ? E : N * 32;
    k_pre<<<(mx + 255) / 256, 256, 0, stream>>>(dst, E, deg, batch, N, G, goff, x, xb);

    // ---- CSR offsets in ONE launch (all NB blocks co-resident; NB<=256 holds for N<=256K) ----
    k_scan<<<NB, 256, 0, stream>>>(deg, N, NB, bsum, done, csr_off);
    k_fill<<<(E + 255) / 256, 256, 0, stream>>>(src, dst, eattr, E, csr_off, fill, csr_src, A_csr);
    k_self<<<(N + 3) / 4, 256, 0, stream>>>(csr_off, N, csr_src, A_csr);

    // ---- k_gat launch geometry: npw=4 (measured sweet spot) ----
    int npw = 4;
    int gblocks = (N + npw * 4 - 1) / (npw * 4);

    // ---- block 1 ----
    k_tf_mfma<64, 24, NODE_D, true><<<512, 256, 0, stream>>>(
        xb, Wl1, bl1, Wr1, br1, Wres, bres, xlb, xrb, resb, N);
    k_gat<false><<<gblocks, 256, 0, stream>>>(csr_off, csr_src, A_csr,
                                              xlb, xrb, resb, We1, att1, ab1, lng1, lnb1,
                                              hb, nullptr, nullptr, N, npw);

    // ---- block 2 (pool fused into epilogue; segment-accumulated atomics) ----
    k_tf_mfma<128, 16, 128, true><<<512, 256, 0, stream>>>(
        hb, Wl2, bl2, Wr2, br2, Wr2, br2, xlb, xrb, xrb, N);
    k_gat<true><<<gblocks, 256, 0, stream>>>(csr_off, csr_src, A_csr,
                                             xlb, xrb, hb, We2, att2, ab2, lng2, lnb2,
                                             (u16*)nullptr, batch, gsum, N, npw);

    // ---- readout MLP on pooled sums ----
    k_read<<<G, 128, 0, stream>>>(gsum, goff, Wd1, bd1, Wd2, bd2, (float*)d_out, G);
}

// Round 11
// 502.130 us; speedup vs baseline: 1.1212x; 1.0578x over previous
//
#include <hip/hip_runtime.h>

typedef unsigned short u16;
typedef unsigned int   u32;
typedef __attribute__((ext_vector_type(8))) short short8;
typedef __attribute__((ext_vector_type(4))) float float4v;
typedef __attribute__((ext_vector_type(2))) float float2v;
typedef __attribute__((ext_vector_type(4), aligned(4))) float float4u;   // dword-aligned vec load

#define NODE_D   38
#define EDGE_D   13
#define D_OUT    128
#define NEG_SLOPE 0.2f
#define LN_EPS   1e-5f

__device__ __forceinline__ float bf2f(u16 v) { return __uint_as_float(((u32)v) << 16); }
__device__ __forceinline__ u16 f2bf(float f) {
    u32 u = __float_as_uint(f);
    u += 0x7fffu + ((u >> 16) & 1u);   // round-to-nearest-even
    return (u16)(u >> 16);
}

// ---- DPP 16-lane all-reduce: 4 VALU adds, no LDS pipe, no lgkm waits ----
template <int CTRL>
__device__ __forceinline__ float dpp_radd(float x) {
    int t = __builtin_amdgcn_update_dpp(0, __float_as_int(x), CTRL, 0xf, 0xf, true);
    return x + __int_as_float(t);
}
__device__ __forceinline__ float reduce16(float p) {
    p = dpp_radd<0xB1>(p);    // quad_perm [1,0,3,2]  : xor 1
    p = dpp_radd<0x4E>(p);    // quad_perm [2,3,0,1]  : xor 2
    p = dpp_radd<0x124>(p);   // row_ror:4
    p = dpp_radd<0x128>(p);   // row_ror:8 -> all 16 lanes hold group sum
    return p;
}
__device__ __forceinline__ float reduce64(float v) {
    v = reduce16(v);
    v += __shfl_xor(v, 16, 64);
    v += __shfl_xor(v, 32, 64);
    return v;
}

// ---------------- fused: degree count + graph offsets + x->bf16 cast ----------------
__global__ void k_pre(const int* __restrict__ dst, int E, int* __restrict__ deg,
                      const int* __restrict__ batch, int N, int G, int* __restrict__ goff,
                      const float* __restrict__ x, u16* __restrict__ xb) {
    int i = blockIdx.x * blockDim.x + threadIdx.x;
    if (i < E) atomicAdd(deg + dst[i], 1);
    if (i < N) {
        int b = batch[i];
        int prev = (i == 0) ? -1 : batch[i - 1];
        for (int g = prev + 1; g <= b; g++) goff[g] = i;
        if (i == N - 1)
            for (int g = b + 1; g <= G; g++) goff[g] = N;
    }
    if (i < N * 32) {   // x (f32, 38 wide) -> bf16 rows padded to 64
        int n = i >> 5, kk = (i & 31) * 2;
        float f0 = 0.f, f1 = 0.f;
        if (kk < NODE_D) {   // NODE_D even -> pair never straddles row end; 8B-aligned
            float2v v = *(const float2v*)(x + (size_t)n * NODE_D + kk);
            f0 = v[0]; f1 = v[1];
        }
        ((u32*)xb)[(size_t)n * 32 + (i & 31)] = (u32)f2bf(f0) | ((u32)f2bf(f1) << 16);
    }
}

// ---------------- single-launch scan (all chunk-blocks co-resident; spin barrier) ----------
// slot count per node = deg + 1 (self loop). Requires nb <= 256 (N <= 256*1024).
#define SCAN_CHUNK 1024
__global__ __launch_bounds__(256) void k_scan(
    const int* __restrict__ cnt, int N, int nb,
    int* __restrict__ bsum, int* __restrict__ done, int* __restrict__ off) {
    __shared__ int wtot[4];
    __shared__ int sh[256];
    int base = blockIdx.x * SCAN_CHUNK;
    int t = threadIdx.x, lane = t & 63, w = t >> 6;
    int v[4]; int s = 0;
#pragma unroll
    for (int i = 0; i < 4; i++) { int idx = base + t * 4 + i; v[i] = (idx < N) ? cnt[idx] + 1 : 0; s += v[i]; }
    int inc = s;
#pragma unroll
    for (int ofs = 1; ofs < 64; ofs <<= 1) {
        int x = __shfl_up(inc, ofs, 64);
        if (lane >= ofs) inc += x;
    }
    if (lane == 63) wtot[w] = inc;
    __syncthreads();
    int wofs = 0;
    for (int i = 0; i < w; i++) wofs += wtot[i];
    int btot = wtot[0] + wtot[1] + wtot[2] + wtot[3];
    if (t == 0) {
        __hip_atomic_store(&bsum[blockIdx.x], btot, __ATOMIC_RELEASE, __HIP_MEMORY_SCOPE_AGENT);
        atomicAdd(done, 1);                                  // device-scope arrive
        while (__hip_atomic_load(done, __ATOMIC_ACQUIRE, __HIP_MEMORY_SCOPE_AGENT) < nb) {}
    }
    __syncthreads();
    // exclusive block offset (agent-scope loads: cross-XCD safe)
    int val = (t < blockIdx.x) ? __hip_atomic_load(&bsum[t], __ATOMIC_ACQUIRE, __HIP_MEMORY_SCOPE_AGENT) : 0;
    sh[t] = val; __syncthreads();
    for (int ofs = 128; ofs > 0; ofs >>= 1) {
        if (t < ofs) sh[t] += sh[t + ofs];
        __syncthreads();
    }
    int boffb = sh[0];
    int run = boffb + wofs + (inc - s);
#pragma unroll
    for (int i = 0; i < 4; i++) {
        int idx = base + t * 4 + i;
        if (idx < N) off[idx] = run;
        run += v[i];
    }
    if (blockIdx.x == nb - 1 && t == 0) off[N] = boffb + btot;
}

// ---------------- CSR fill: scatter src AND the bf16 A-row (16-wide, padded) ----------------
__global__ void k_fill(const int* __restrict__ src, const int* __restrict__ dst,
                       const float* __restrict__ eattr, int E,
                       const int* __restrict__ csr_off, int* __restrict__ fill,
                       int* __restrict__ csr_src, u16* __restrict__ A) {
    int e = blockIdx.x * blockDim.x + threadIdx.x;
    if (e >= E) return;
    int d = dst[e];
    int pos = csr_off[d] + atomicAdd(fill + d, 1);
    csr_src[pos] = src[e];
    const float* ep = eattr + (size_t)e * EDGE_D;
    float4u v0 = *(const float4u*)(ep);          // dwordx4, dword-aligned
    float4u v1 = *(const float4u*)(ep + 4);
    float4u v2 = *(const float4u*)(ep + 8);
    float   v3 = ep[12];
    u16 row[16];
#pragma unroll
    for (int k = 0; k < 4; k++) { row[k] = f2bf(v0[k]); row[4 + k] = f2bf(v1[k]); row[8 + k] = f2bf(v2[k]); }
    row[12] = f2bf(v3);
#pragma unroll
    for (int k = EDGE_D; k < 16; k++) row[k] = 0;
    uint4* rp = (uint4*)(A + (size_t)pos * 16);
    rp[0] = (uint4){(u32)row[0] | ((u32)row[1] << 16), (u32)row[2] | ((u32)row[3] << 16),
                    (u32)row[4] | ((u32)row[5] << 16), (u32)row[6] | ((u32)row[7] << 16)};
    rp[1] = (uint4){(u32)row[8] | ((u32)row[9] << 16), (u32)row[10] | ((u32)row[11] << 16),
                    (u32)row[12] | ((u32)row[13] << 16), (u32)row[14] | ((u32)row[15] << 16)};
}

// ---------------- self rows: one WAVE per node, coalesced 4-row x 16-ch lanes ----------------
__global__ __launch_bounds__(256) void k_self(const int* __restrict__ csr_off, int N,
                                              int* __restrict__ csr_src, u16* __restrict__ A) {
    int wave = blockIdx.x * 4 + (threadIdx.x >> 6);
    if (wave >= N) return;
    int lane = threadIdx.x & 63;
    int r = lane >> 4, k = lane & 15;
    int b = csr_off[wave], e2 = csr_off[wave + 1] - 1;   // e2 = self slot
    float s = 0.f;
    for (int j = b + r; j < e2; j += 4)                  // lanes cover 4 rows x 16 ch: 128B/iter
        s += bf2f(A[(size_t)j * 16 + k]);
    s += __shfl_xor(s, 16, 64);
    s += __shfl_xor(s, 32, 64);
    if (lane < 16) {
        u16 v = (k < EDGE_D) ? f2bf(s / fmaxf((float)(e2 - b), 1.f)) : (u16)0;
        A[(size_t)e2 * 16 + k] = v;
        if (k == 0) csr_src[e2] = wave;
    }
}

// ---------------- MFMA multi-output transform (transposed store: 8B ushort4 per lane) ------
template <int KPAD, int CT, int KREAL, bool IN_BF16>
__global__ __launch_bounds__(256) void k_tf_mfma(
    const void* __restrict__ in_v,
    const float* __restrict__ W0, const float* __restrict__ b0,
    const float* __restrict__ W1, const float* __restrict__ b1,
    const float* __restrict__ W2, const float* __restrict__ b2,
    u16* __restrict__ o0, u16* __restrict__ o1, u16* __restrict__ o2,
    int N) {
    constexpr int RS = KPAD + 8;
    __shared__ u16 Bsw[CT * 16 * RS];
    __shared__ float bsh[CT * 16];
    const float* Ws[3] = {W0, W1, W2};
    const float* bs[3] = {b0, b1, b2};
    u16* outs[3] = {o0, o1, o2};
    int t = threadIdx.x;
    for (int i = t; i < CT * 16 * KPAD; i += 256) {
        int c = i / KPAD, k = i - c * KPAD;
        float v = (k < KREAL) ? Ws[c >> 7][(size_t)k * 128 + (c & 127)] : 0.f;
        Bsw[c * RS + k] = f2bf(v);
    }
    for (int i = t; i < CT * 16; i += 256) bsh[i] = bs[i >> 7][i & 127];
    __syncthreads();

    int wid = t >> 6, lane = t & 63;
    int quad = lane >> 4, m = lane & 15;

    for (int g0 = blockIdx.x * 64; g0 < N; g0 += gridDim.x * 64) {
        int na = g0 + wid * 16 + m;
        if (na > N - 1) na = N - 1;
        short8 a[KPAD / 32];
        if (IN_BF16) {
            const u16* in = (const u16*)in_v;
#pragma unroll
            for (int kc = 0; kc < KPAD / 32; kc++)
                a[kc] = *(const short8*)(in + (size_t)na * KPAD + kc * 32 + quad * 8);
        } else {
            const float* in = (const float*)in_v;
#pragma unroll
            for (int kc = 0; kc < KPAD / 32; kc++)
#pragma unroll
                for (int j = 0; j < 8; j++) {
                    int k = kc * 32 + quad * 8 + j;
                    float v = (k < KREAL) ? in[(size_t)na * KREAL + k] : 0.f;
                    a[kc][j] = (short)f2bf(v);
                }
        }
        float4v acc[CT];
#pragma unroll
        for (int ct = 0; ct < CT; ct++) acc[ct] = (float4v){0.f, 0.f, 0.f, 0.f};
#pragma unroll
        for (int ct = 0; ct < CT; ct++) {
#pragma unroll
            for (int kc = 0; kc < KPAD / 32; kc++) {
                short8 b = *(const short8*)(&Bsw[(ct * 16 + m) * RS + kc * 32 + quad * 8]);
                // swapped operands -> transposed D: lane m = node, quad*4+r = out-col
                acc[ct] = __builtin_amdgcn_mfma_f32_16x16x32_bf16(b, a[kc], acc[ct], 0, 0, 0);
            }
        }
        int node = g0 + wid * 16 + m;
        if (node < N) {
#pragma unroll
            for (int ct = 0; ct < CT; ct++) {
                int colb = ct * 16 + quad * 4;          // 4 consecutive out-cols
                u16* op = outs[colb >> 7];
                int cc = colb & 127;
                float4v bq = *(const float4v*)&bsh[colb];
                ushort4 wv;
                wv.x = f2bf(acc[ct][0] + bq[0]);
                wv.y = f2bf(acc[ct][1] + bq[1]);
                wv.z = f2bf(acc[ct][2] + bq[2]);
                wv.w = f2bf(acc[ct][3] + bq[3]);
                *(ushort4*)(op + (size_t)node * 128 + cc) = wv;   // 8B store
            }
        }
    }
}

// ---------------- fused GATv2 block: depth-4 xl gather ring + wave-entry node-row preload --
// POOL=true -> per-wave segment accumulation in registers, atomicAdd flush on graph boundary.
template <bool POOL>
__global__ __launch_bounds__(256) void k_gat(
    const int* __restrict__ csr_off, const int* __restrict__ csr_src,
    const u16* __restrict__ A_csr,
    const u16* __restrict__ xl, const u16* __restrict__ xr,
    const u16* __restrict__ res, const float* __restrict__ We,
    const float* __restrict__ att, const float* __restrict__ ab,
    const float* __restrict__ lng, const float* __restrict__ lnb,
    u16* __restrict__ hout, const int* __restrict__ batch, float* __restrict__ gsum,
    int N, int npw) {
    int t = threadIdx.x;
    int wid = t >> 6, lane = t & 63;
    int wave = blockIdx.x * 4 + wid;
    int n0 = wave * npw;
    if (n0 >= N) return;
    int n1 = n0 + npw; if (n1 > N) n1 = N;

    // ---- node-invariant preamble (once per wave) ----
    float2v we2[EDGE_D];
#pragma unroll
    for (int k = 0; k < EDGE_D; k++)
        we2[k] = (float2v){We[k * D_OUT + 2 * lane], We[k * D_OUT + 2 * lane + 1]};
    float a0 = att[2 * lane], a1 = att[2 * lane + 1];
    float abv0 = ab[2 * lane], abv1 = ab[2 * lane + 1];
    float lg0 = lng[2 * lane], lg1 = lng[2 * lane + 1];
    float lb0 = lnb[2 * lane], lb1 = lnb[2 * lane + 1];

    const u32* xl32 = (const u32*)xl;
    const u32* xr32 = (const u32*)xr;
    const u32* res32 = (const u32*)res;
    int wbeg = csr_off[n0];
    int wend = csr_off[n1];
    int nedge = wend - wbeg;

    // ---- pooled-segment registers (POOL path) ----
    float ps0 = 0.f, ps1 = 0.f;
    int gcur = POOL ? batch[n0] : -1;

    auto finish = [&](int n, float ssum, float2v acc2, u32 rw) {
        float inv = 1.f / ssum;
        float o0 = acc2[0] * inv + abv0;
        float o1 = acc2[1] * inv + abv1;
        o0 = (o0 > 0.f) ? o0 : (__expf(o0) - 1.f);   // ELU
        o1 = (o1 > 0.f) ? o1 : (__expf(o1) - 1.f);
        o0 += bf2f((u16)(rw & 0xffff));
        o1 += bf2f((u16)(rw >> 16));
        // LN via E[x], E[x^2]: the two reduce64 chains are independent -> ILP overlap
        float s1 = reduce64(o0 + o1);
        float s2 = reduce64(o0 * o0 + o1 * o1);
        float mu = s1 * (1.f / 128.f);
        float var = s2 * (1.f / 128.f) - mu * mu;
        float rs = rsqrtf(var + LN_EPS);
        float h0 = (o0 - mu) * rs * lg0 + lb0;
        float h1 = (o1 - mu) * rs * lg1 + lb1;
        if (POOL) {
            int g = batch[n];                         // wave-uniform (n is wave-uniform)
            if (g != gcur) {                          // flush previous segment
                atomicAdd(gsum + (size_t)gcur * 128 + 2 * lane, ps0);
                atomicAdd(gsum + (size_t)gcur * 128 + 2 * lane + 1, ps1);
                ps0 = 0.f; ps1 = 0.f; gcur = g;
            }
            ps0 += h0; ps1 += h1;
        } else {
            ((u32*)hout)[(size_t)n * 64 + lane] = (u32)f2bf(h0) | ((u32)f2bf(h1) << 16);
        }
    };

    const float2v z0v = (float2v){0.f, 0.f};

    if (nedge <= 64) {
        // ---- fast path: wave src indices preloaded; xl gather ring depth 4 ----
        int last = nedge - 1;
        int sv = csr_src[wbeg + ((lane < nedge) ? lane : last)];
        int f0 = __builtin_amdgcn_readlane(sv, 0);
        int f1 = __builtin_amdgcn_readlane(sv, (1 <= last) ? 1 : last);
        int f2 = __builtin_amdgcn_readlane(sv, (2 <= last) ? 2 : last);
        int f3 = __builtin_amdgcn_readlane(sv, (3 <= last) ? 3 : last);
        u32 xw0 = xl32[(size_t)f0 * 64 + lane];   // 4 row-gathers in flight per wave
        u32 xw1 = xl32[(size_t)f1 * 64 + lane];
        u32 xw2 = xl32[(size_t)f2 * 64 + lane];
        u32 xw3 = xl32[(size_t)f3 * 64 + lane];
        // A-row: wave-uniform -> force scalar (SMEM) load path
        int wbu = __builtin_amdgcn_readfirstlane(wbeg);
        const uint4* ap = (const uint4*)(A_csr + (size_t)wbu * 16);
        uint4 aq0 = ap[0], aq1 = ap[1];
        // NEW: preload all npw nodes' xr + res rows at wave entry (8 independent loads,
        // all in flight together; consumed via statically-indexed registers below)
        int nnl = n1 - 1;
        int nn1 = (n0 + 1 < n1) ? n0 + 1 : nnl;
        int nn2 = (n0 + 2 < n1) ? n0 + 2 : nnl;
        int nn3 = (n0 + 3 < n1) ? n0 + 3 : nnl;
        u32 xrp0 = xr32[(size_t)n0 * 64 + lane];
        u32 xrp1 = xr32[(size_t)nn1 * 64 + lane];
        u32 xrp2 = xr32[(size_t)nn2 * 64 + lane];
        u32 xrp3 = xr32[(size_t)nn3 * 64 + lane];
        u32 rwp0 = res32[(size_t)n0 * 64 + lane];
        u32 rwp1 = res32[(size_t)nn1 * 64 + lane];
        u32 rwp2 = res32[(size_t)nn2 * 64 + lane];
        u32 rwp3 = res32[(size_t)nn3 * 64 + lane];

        int i = wbeg;
        auto do_node = [&](int n, u32 xrw, u32 rw) {
            int end = csr_off[n + 1];
            float2v xr2 = (float2v){bf2f((u16)(xrw & 0xffff)), bf2f((u16)(xrw >> 16))};
            float ssum = 0.f;
            float2v acc2 = (float2v){0.f, 0.f};
            for (; i < end; i++) {
                // prefetch: xl four ahead, A one ahead (scalar-indexed)
                int j4 = i + 4 - wbeg; if (j4 > last) j4 = last;
                int f4 = __builtin_amdgcn_readlane(sv, j4);
                u32 xwN = xl32[(size_t)f4 * 64 + lane];
                int j1n = i + 1 - wbeg; if (j1n > last) j1n = last;
                int ipu = __builtin_amdgcn_readfirstlane(wbeg + j1n);
                const uint4* apn = (const uint4*)(A_csr + (size_t)ipu * 16);
                uint4 an0 = apn[0], an1 = apn[1];

                u32 dw[8] = {aq0.x, aq0.y, aq0.z, aq0.w, aq1.x, aq1.y, aq1.z, aq1.w};
                float2v eeA = (float2v){0.f, 0.f}, eeB = (float2v){0.f, 0.f};
#pragma unroll
                for (int k = 0; k < EDGE_D; k++) {
                    u32 d = dw[k >> 1];
                    float av = __uint_as_float((k & 1) ? (d & 0xffff0000u) : (d << 16));
                    if ((k >> 1) & 1) eeB += we2[k] * av;   // two interleaved fma chains
                    else             eeA += we2[k] * av;
                }
                float2v xs = (float2v){bf2f((u16)(xw0 & 0xffff)), bf2f((u16)(xw0 >> 16))};
                float2v z = (xs + xr2) + (eeA + eeB);
                float2v lz = __builtin_elementwise_max(z, z0v) + __builtin_elementwise_min(z, z0v) * NEG_SLOPE;
                float p = lz[0] * a0 + lz[1] * a1;
                p = reduce16(p);                    // DPP, VALU-only
                float wgt = __expf(p);              // logits are O(1): no max-subtraction
                ssum += wgt;
                acc2 += xs * wgt;
                xw0 = xw1; xw1 = xw2; xw2 = xw3; xw3 = xwN;
                aq0 = an0; aq1 = an1;
            }
            finish(n, ssum, acc2, rw);
        };
        do_node(n0, xrp0, rwp0);
        if (n0 + 1 < n1) do_node(n0 + 1, xrp1, rwp1);
        if (n0 + 2 < n1) do_node(n0 + 2, xrp2, rwp2);
        if (n0 + 3 < n1) do_node(n0 + 3, xrp3, rwp3);
    } else {
        // ---- generic fallback (nedge > 64; rare at npw=4) ----
        int cl = wend - 1;
        int f = csr_src[wbeg];
        u32 xw = xl32[(size_t)f * 64 + lane];
        int wbu = __builtin_amdgcn_readfirstlane(wbeg);
        const uint4* ap = (const uint4*)(A_csr + (size_t)wbu * 16);
        uint4 aq0 = ap[0], aq1 = ap[1];
        int i = wbeg;
        for (int n = n0; n < n1; n++) {
            int end = csr_off[n + 1];
            u32 xrw = xr32[(size_t)n * 64 + lane];
            u32 rw = res32[(size_t)n * 64 + lane];   // issued early: hides under edge loop
            float2v xr2 = (float2v){bf2f((u16)(xrw & 0xffff)), bf2f((u16)(xrw >> 16))};
            float ssum = 0.f;
            float2v acc2 = (float2v){0.f, 0.f};
            for (; i < end; i++) {
                u32 xwc = xw; uint4 q0 = aq0, q1 = aq1;
                int ip = (i + 1 < wend) ? i + 1 : cl;
                f = csr_src[ip];
                xw = xl32[(size_t)f * 64 + lane];
                int ipu = __builtin_amdgcn_readfirstlane(ip);
                const uint4* ap2 = (const uint4*)(A_csr + (size_t)ipu * 16);
                aq0 = ap2[0]; aq1 = ap2[1];
                u32 dw[8] = {q0.x, q0.y, q0.z, q0.w, q1.x, q1.y, q1.z, q1.w};
                float2v eeA = (float2v){0.f, 0.f}, eeB = (float2v){0.f, 0.f};
#pragma unroll
                for (int k = 0; k < EDGE_D; k++) {
                    u32 d = dw[k >> 1];
                    float av = __uint_as_float((k & 1) ? (d & 0xffff0000u) : (d << 16));
                    if ((k >> 1) & 1) eeB += we2[k] * av;
                    else             eeA += we2[k] * av;
                }
                float2v xs = (float2v){bf2f((u16)(xwc & 0xffff)), bf2f((u16)(xwc >> 16))};
                float2v z = (xs + xr2) + (eeA + eeB);
                float2v lz = __builtin_elementwise_max(z, z0v) + __builtin_elementwise_min(z, z0v) * NEG_SLOPE;
                float p = lz[0] * a0 + lz[1] * a1;
                p = reduce16(p);
                float wgt = __expf(p);
                ssum += wgt;
                acc2 += xs * wgt;
            }
            finish(n, ssum, acc2, rw);
        }
    }

    // ---- final segment flush (POOL path) ----
    if (POOL) {
        atomicAdd(gsum + (size_t)gcur * 128 + 2 * lane, ps0);
        atomicAdd(gsum + (size_t)gcur * 128 + 2 * lane + 1, ps1);
    }
}

// ---------------- readout MLP on pre-pooled sums ----------------
__global__ __launch_bounds__(128) void k_read(
    const float* __restrict__ gsum, const int* __restrict__ goff,
    const float* __restrict__ Wd1, const float* __restrict__ bd1,
    const float* __restrict__ Wd2, const float* __restrict__ bd2,
    float* __restrict__ out, int G) {
    __shared__ float psh[128];
    __shared__ float rsh[2][64];
    int g = blockIdx.x;
    int t = threadIdx.x;
    int cnt = goff[g + 1] - goff[g];
    float inv = 1.f / fmaxf((float)cnt, 1.f);
    psh[t] = gsum[(size_t)g * 128 + t] * inv;
    __syncthreads();
    int j = t & 63, hw = t >> 6;
    float acc = (hw == 0) ? bd1[j] : 0.f;
    int k0 = hw * 64;
    for (int k = k0; k < k0 + 64; k++)
        acc += psh[k] * Wd1[k * 64 + j];
    rsh[hw][j] = acc;
    __syncthreads();
    if (t < 64) {
        float a = fmaxf(rsh[0][t] + rsh[1][t], 0.f);
        float v = a * Wd2[t];
#pragma unroll
        for (int mk = 1; mk < 64; mk <<= 1) v += __shfl_xor(v, mk, 64);
        if (t == 0) out[g] = v + bd2[0];
    }
}

extern "C" void kernel_launch(void* const* d_in, const int* in_sizes, int n_in,
                              void* d_out, int out_size, void* d_ws, size_t ws_size,
                              hipStream_t stream) {
    const float* x     = (const float*)d_in[0];
    const int*   eidx  = (const int*)d_in[1];
    const float* eattr = (const float*)d_in[2];
    const int*   batch = (const int*)d_in[3];
    const float* Wl1 = (const float*)d_in[4],  *bl1 = (const float*)d_in[5];
    const float* Wr1 = (const float*)d_in[6],  *br1 = (const float*)d_in[7];
    const float* We1 = (const float*)d_in[8],  *att1 = (const float*)d_in[9],  *ab1 = (const float*)d_in[10];
    const float* lng1 = (const float*)d_in[11], *lnb1 = (const float*)d_in[12];
    const float* Wres = (const float*)d_in[13], *bres = (const float*)d_in[14];
    const float* Wl2 = (const float*)d_in[15], *bl2 = (const float*)d_in[16];
    const float* Wr2 = (const float*)d_in[17], *br2 = (const float*)d_in[18];
    const float* We2 = (const float*)d_in[19], *att2 = (const float*)d_in[20], *ab2 = (const float*)d_in[21];
    const float* lng2 = (const float*)d_in[22], *lnb2 = (const float*)d_in[23];
    const float* Wd1 = (const float*)d_in[24], *bd1 = (const float*)d_in[25];
    const float* Wd2 = (const float*)d_in[26], *bd2 = (const float*)d_in[27];

    int N = in_sizes[0] / NODE_D;
    int E = in_sizes[1] / 2;
    int G = out_size;
    int EN = E + N;
    const int* src = eidx;
    const int* dst = eidx + E;

    char* w = (char*)d_ws;
    auto alloc = [&](size_t bytes) -> char* {
        char* p = w;
        w += (bytes + 255) & ~(size_t)255;
        return p;
    };
    int NB = (N + SCAN_CHUNK - 1) / SCAN_CHUNK;
    // ---- persistent buffers ----
    int*   csr_off  = (int*)alloc((size_t)(N + 1) * 4);
    int*   csr_src  = (int*)alloc((size_t)EN * 4);
    u16*   A_csr    = (u16*)alloc((size_t)(EN + 64) * 16 * 2);
    u16*   xb       = (u16*)alloc((size_t)N * 64 * 2);     // bf16 x, padded 38->64
    u16*   xlb      = (u16*)alloc((size_t)N * D_OUT * 2);
    u16*   xrb      = (u16*)alloc((size_t)N * D_OUT * 2);
    u16*   resb     = (u16*)alloc((size_t)N * D_OUT * 2);  // res1
    u16*   hb       = (u16*)alloc((size_t)N * D_OUT * 2);
    int*   goff     = (int*)alloc((size_t)(G + 1) * 4);
    // ---- zeroed scratch (deg/fill/gsum/done adjacent -> one memset) ----
    size_t szN = ((size_t)N * 4 + 255) & ~(size_t)255;
    size_t szG = ((size_t)G * 128 * 4 + 255) & ~(size_t)255;
    char*  zp   = alloc(2 * szN + szG + 256);
    int*   deg  = (int*)zp;
    int*   fill = (int*)(zp + szN);
    float* gsum = (float*)(zp + 2 * szN);
    int*   done = (int*)(zp + 2 * szN + szG);
    int*   bsum = (int*)alloc((size_t)(NB + 1) * 4);

    hipMemsetAsync(zp, 0, 2 * szN + szG + 256, stream);

    // ---- degree count + graph offsets + x cast (fused) ----
    int mx = (E > N * 32) ? E : N * 32;
    k_pre<<<(mx + 255) / 256, 256, 0, stream>>>(dst, E, deg, batch, N, G, goff, x, xb);

    // ---- CSR offsets in ONE launch (all NB blocks co-resident; NB<=256 holds for N<=256K) ----
    k_scan<<<NB, 256, 0, stream>>>(deg, N, NB, bsum, done, csr_off);
    k_fill<<<(E + 255) / 256, 256, 0, stream>>>(src, dst, eattr, E, csr_off, fill, csr_src, A_csr);
    k_self<<<(N + 3) / 4, 256, 0, stream>>>(csr_off, N, csr_src, A_csr);

    // ---- k_gat launch geometry: npw=4 (measured sweet spot) ----
    int npw = 4;
    int gblocks = (N + npw * 4 - 1) / (npw * 4);

    // ---- block 1 ----
    k_tf_mfma<64, 24, NODE_D, true><<<512, 256, 0, stream>>>(
        xb, Wl1, bl1, Wr1, br1, Wres, bres, xlb, xrb, resb, N);
    k_gat<false><<<gblocks, 256, 0, stream>>>(csr_off, csr_src, A_csr,
                                              xlb, xrb, resb, We1, att1, ab1, lng1, lnb1,
                                              hb, nullptr, nullptr, N, npw);

    // ---- block 2 (pool fused into epilogue; segment-accumulated atomics) ----
    k_tf_mfma<128, 16, 128, true><<<512, 256, 0, stream>>>(
        hb, Wl2, bl2, Wr2, br2, Wr2, br2, xlb, xrb, xrb, N);
    k_gat<true><<<gblocks, 256, 0, stream>>>(csr_off, csr_src, A_csr,
                                             xlb, xrb, hb, We2, att2, ab2, lng2, lnb2,
                                             (u16*)nullptr, batch, gsum, N, npw);

    // ---- readout MLP on pooled sums ----
    k_read<<<G, 128, 0, stream>>>(gsum, goff, Wd1, bd1, Wd2, bd2, (float*)d_out, G);
}